// Round 12
// baseline (176.962 us; speedup 1.0000x reference)
//
#include <hip/hip_runtime.h>
#include <math.h>

#define NB 4
#define NC 128
#define NH 128
#define NW 128
#define NHW (NH*NW)
#define NCOUT 128

// ws float offsets (SY/SX/MK regions no longer used)
#define WOFF_OFF 3538944    // 36 slabs [64][36] bf16 (offset-conv W)
#define WMAIN_OFF 3580416   // 36 slabs [128][36] bf16 (main W)
#define XT_OFF 3663360      // bf16 xT[b][cg16][y][x][8ch] : 8388608 shorts

typedef short short8 __attribute__((ext_vector_type(8)));
typedef float f32x4 __attribute__((ext_vector_type(4)));

__device__ inline short f2bf(float f) {
    unsigned u = __float_as_uint(f);
    u = (u + 0x7FFFu + ((u >> 16) & 1u)) >> 16;   // RNE
    return (short)u;
}
__device__ inline unsigned pack2(float lo, float hi) {
    unsigned r;
    asm("v_cvt_pk_bf16_f32 %0, %1, %2" : "=v"(r) : "v"(lo), "v"(hi));
    return r;
}
__device__ inline float bflo(unsigned u) { return __uint_as_float(u << 16); }
__device__ inline float bfhi(unsigned u) { return __uint_as_float(u & 0xffff0000u); }
__device__ inline unsigned pkf16(float a, float b) {
    auto h = __builtin_amdgcn_cvt_pkrtz(a, b);   // __fp16 ext_vector(2)
    unsigned r; __builtin_memcpy(&r, &h, 4); return r;
}
__device__ inline float f16f(unsigned s) {
    unsigned short us = (unsigned short)s;
    __fp16 h; __builtin_memcpy(&h, &us, 2); return (float)h;
}
__device__ inline void gload_lds16(const void* g, void* l) {
    __builtin_amdgcn_global_load_lds(
        (const __attribute__((address_space(1))) unsigned int*)g,
        (__attribute__((address_space(3))) unsigned int*)l, 16, 0, 0);
}

// ---------------------------------------------------------------------------
// wtrans: offset table 36 slabs [64][36] + main table 36 slabs [128][36] padded
// ---------------------------------------------------------------------------
__global__ void wtrans_kernel(const float* __restrict__ w_off,
                              const float* __restrict__ weight,
                              float* __restrict__ ws)
{
    int i = blockIdx.x * 256 + threadIdx.x;
    if (i < 36*2304) {
        int s = i / 2304, rem = i - s*2304;
        int row = rem / 36, c = rem - row*36;
        int chunk = s / 9, k2 = s - 9*chunk;
        float v = (row < 54 && c < 32) ? w_off[(row*NC + chunk*32 + c)*9 + k2] : 0.f;
        ((short*)(ws + WOFF_OFF))[i] = f2bf(v);
    } else if (i < 36*2304 + 36*4608) {
        int j = i - 36*2304;
        int s = j / 4608, rem = j - s*4608;
        int row = rem / 36, c = rem - row*36;
        int chunk = s / 9, k2 = s - 9*chunk;
        float v = (c < 32) ? weight[(row*NC + chunk*32 + c)*9 + k2] : 0.f;
        ((short*)(ws + WMAIN_OFF))[j] = f2bf(v);
    }
}

// ---------------------------------------------------------------------------
// xtrans: x NCHW fp32 -> xT[b][cg][y][x][8ch] bf16. Pure BW.
// ---------------------------------------------------------------------------
__global__ __launch_bounds__(256) void xtrans_kernel(
    const float* __restrict__ x, float* __restrict__ ws)
{
    short* xT = (short*)(ws + XT_OFF);
    const int bid = blockIdx.x;
    const int ys = bid & 15, cg = (bid >> 4) & 15, b = bid >> 8;
    const int col = threadIdx.x & 127, rr = threadIdx.x >> 7;
    const float* xb = x + ((long)(b*NC + cg*8))*NHW;
#pragma unroll
    for (int yy = 0; yy < 4; ++yy) {
        const int y = ys*8 + yy*2 + rr;
        const float* p = xb + y*NW + col;
        float v[8];
#pragma unroll
        for (int q = 0; q < 8; ++q) v[q] = p[q*NHW];
        uint4 u = make_uint4(pack2(v[0],v[1]), pack2(v[2],v[3]),
                             pack2(v[4],v[5]), pack2(v[6],v[7]));
        *(uint4*)&xT[(((long)(b*16+cg)*NH + y)*NW + col)*8] = u;
    }
}

// ---------------------------------------------------------------------------
// fused: block = (b, ho), 512 threads = 8 waves.
//  Phase 1: offset conv for row ho (GEMM over xT) -> convout in LDS.
//  Phase 2: bilinear params from convout -> pI/pWp.
//  Phase 3: deform conv (R11 structure).
// LDS region C (38912 B) overlaid: {convout[54][132]f32 + woff slabs} then
// {vals[2][128][40] + wslab[2][4608]}.
// ---------------------------------------------------------------------------
__global__ __launch_bounds__(512, 4) void fused_kernel(
    const float* __restrict__ b_off, const float* __restrict__ bias,
    float* __restrict__ ws, float* __restrict__ out)
{
    __shared__ short4 pI[18][128];        // 18432 B
    __shared__ uint2  pWp[18][128];       // 18432 B
    __shared__ char   creg[38912];        // overlaid region C

    float* convout = (float*)creg;                               // [54][132]
    short (*wsoff)[2304] = (short(*)[2304])(creg + 28512);       // [2][2304]
    short (*vals)[128][40] = (short(*)[128][40])creg;            // [2][128][40]
    short (*wslab)[4608] = (short(*)[4608])(creg + 20480);       // [2][4608]

    int bid = blockIdx.x;
    bid = (bid & 7) * 64 + (bid >> 3);      // XCD swizzle (512 = 8*64)
    const int b   = bid >> 7;
    const int ho  = bid & 127;
    const int tid = threadIdx.x;
    const int lane = tid & 63;
    const int wid = tid >> 6;               // 0..7
    const int n = lane & 15, g = lane >> 4;
    const int px1 = wid*16 + n;             // phase-1 pixel
    const int ch  = wid & 1;                // deform: cout half
    const int pxq = wid >> 1;               // deform: px quarter
    const int sp  = tid & 127;              // sampling pixel
    const int sub = tid >> 7;               // sampling 8-ch group
    const short* woff = (const short*)(ws + WOFF_OFF);
    const short* wmn  = (const short*)(ws + WMAIN_OFF);
    const char*  xTb  = (const char*)((const short*)(ws + XT_OFF) + (long)b*16*NHW*8);

    // ================= Phase 1: offset conv (row ho) =================
    {
        f32x4 accO[4];
#pragma unroll
        for (int rf = 0; rf < 4; ++rf) accO[rf] = (f32x4){0.f,0.f,0.f,0.f};

        auto DMAo = [&](int it, int buf) {
            if (tid < 288) gload_lds16(woff + it*2304 + tid*8, &wsoff[buf][tid*8]);
        };
        auto LOADB = [&](int it) -> short8 {
            const int chunk = it/9, k2 = it - 9*chunk;
            const int y = ho + k2/3 - 1, xc = px1 + (k2%3) - 1;
            short8 bf = (short8){0,0,0,0,0,0,0,0};
            if ((unsigned)y < NH && (unsigned)xc < NW)
                bf = *(const short8*)(xTb + ((long)(chunk*4 + g)*NHW + y*NW + xc)*16);
            return bf;
        };

        DMAo(0, 0);
        short8 bcur = LOADB(0);
        __syncthreads();

#pragma unroll 1
        for (int it = 0; it < 36; ++it) {
            const int cur = it & 1, nxt = cur ^ 1;
            short8 bnext;
            if (it < 35) { DMAo(it+1, nxt); bnext = LOADB(it+1); }
            __builtin_amdgcn_sched_barrier(0);
#pragma unroll
            for (int rf = 0; rf < 4; ++rf) {
                short8 af = *(const short8*)&wsoff[cur][(rf*16 + n)*36 + 8*g];
                accO[rf] = __builtin_amdgcn_mfma_f32_16x16x32_bf16(af, bcur, accO[rf], 0,0,0);
            }
            __syncthreads();
            bcur = bnext;
        }

        // raw conv outputs -> convout LDS (no bias yet)
#pragma unroll
        for (int rf = 0; rf < 4; ++rf) {
#pragma unroll
            for (int r = 0; r < 4; ++r) {
                const int cout = 16*rf + 4*g + r;
                if (cout < 54) convout[cout*132 + px1] = accO[rf][r];
            }
        }
    }
    __syncthreads();

    // ================= Phase 2: bilinear params =================
    for (int e = tid; e < 2304; e += 512) {
        const int og = e / 1152, rem = e - og*1152;
        const int k2 = rem >> 7, px = rem & 127;
        const int c_sy = og*18 + 2*k2, c_sx = c_sy + 1, c_m = 36 + og*9 + k2;
        const float sy = convout[c_sy*132 + px] + b_off[c_sy] + (float)(ho - 1 + k2/3);
        const float sx = convout[c_sx*132 + px] + b_off[c_sx] + (float)(px - 1 + k2%3);
        const float mr = convout[c_m*132 + px] + b_off[c_m];
        const float m  = 1.f / (1.f + expf(-mr));
        const float y0f = floorf(sy), x0f = floorf(sx);
        const float ly = sy - y0f, lx = sx - x0f;
        const int y0 = (int)y0f, x0i = (int)x0f;
        const int y1 = y0 + 1, x1 = x0i + 1;
        const bool vy0 = (unsigned)y0 < NH, vy1 = (unsigned)y1 < NH;
        const bool vx0 = (unsigned)x0i < NW, vx1 = (unsigned)x1 < NW;
        const int cy0 = min(max(y0,0),NH-1), cy1 = min(max(y1,0),NH-1);
        const int cx0 = min(max(x0i,0),NW-1), cx1 = min(max(x1,0),NW-1);
        pI[og*9+k2][px] = make_short4(
            (short)(cy0*NW + cx0), (short)(cy0*NW + cx1),
            (short)(cy1*NW + cx0), (short)(cy1*NW + cx1));
        const float W0 = (vy0 && vx0) ? (1.f-ly)*(1.f-lx)*m : 0.f;
        const float W1 = (vy0 && vx1) ? (1.f-ly)*lx*m       : 0.f;
        const float W2 = (vy1 && vx0) ? ly*(1.f-lx)*m       : 0.f;
        const float W3 = (vy1 && vx1) ? ly*lx*m             : 0.f;
        pWp[og*9+k2][px] = make_uint2(pkf16(W0, W1), pkf16(W2, W3));
    }
    __syncthreads();    // convout consumed; region C free for vals/wslab

    // ================= Phase 3: deform =================
    f32x4 acc[4][2];
#pragma unroll
    for (int rf = 0; rf < 4; ++rf) {
        acc[rf][0] = (f32x4){0.f,0.f,0.f,0.f};
        acc[rf][1] = (f32x4){0.f,0.f,0.f,0.f};
    }

    auto DMAm = [&](int slabIdx, int buf) {
        const short* src = wmn + slabIdx*4608;
        gload_lds16(src + tid*8, &wslab[buf][tid*8]);
        if (tid < 64) gload_lds16(src + 4096 + tid*8, &wslab[buf][4096 + tid*8]);
    };
    auto GLOAD = [&](int j, uint4* G) {
        const int chunk = j/9;
        const int row = (j/18)*9 + (j%9);
        const short4 I = pI[row][sp];
        const char* xp = xTb + (long)(chunk*4 + sub)*(NHW*16);
        G[0] = *(const uint4*)(xp + (((int)I.x) << 4));
        G[1] = *(const uint4*)(xp + (((int)I.y) << 4));
        G[2] = *(const uint4*)(xp + (((int)I.z) << 4));
        G[3] = *(const uint4*)(xp + (((int)I.w) << 4));
    };
    auto FIN = [&](int j, uint4* G, int buf) {
        const int row = (j/18)*9 + (j%9);
        const uint2 wp = *(const uint2*)&pWp[row][sp];
        const float W0 = f16f(wp.x), W1 = f16f(wp.x >> 16);
        const float W2 = f16f(wp.y), W3 = f16f(wp.y >> 16);
        uint4 u; unsigned* up = (unsigned*)&u;
        const unsigned* a = (const unsigned*)&G[0];
        const unsigned* bq = (const unsigned*)&G[1];
        const unsigned* c = (const unsigned*)&G[2];
        const unsigned* d = (const unsigned*)&G[3];
#pragma unroll
        for (int e = 0; e < 4; ++e) {
            float lo = W0*bflo(a[e]) + W1*bflo(bq[e]) + W2*bflo(c[e]) + W3*bflo(d[e]);
            float hi = W0*bfhi(a[e]) + W1*bfhi(bq[e]) + W2*bfhi(c[e]) + W3*bfhi(d[e]);
            up[e] = pack2(lo, hi);
        }
        *(uint4*)&vals[buf][sp][sub*8] = u;
    };

    uint4 GA[4], GB[4];
    DMAm(0, 0);
    GLOAD(0, GA);
    FIN(0, GA, 0);                     // auto vmcnt drains DMA(0)+G(0)
    GLOAD(1, GB);                      // stays in flight across barrier
    asm volatile("s_waitcnt lgkmcnt(0)" ::: "memory");
    __builtin_amdgcn_s_barrier();
    __builtin_amdgcn_sched_barrier(0);

    auto BODY = [&](int it, uint4* Gfree, uint4* Gheld) {
        const int cur = it & 1, nxt = cur ^ 1;
        if (it < 35) DMAm(it+1, nxt);
        if (it < 34) GLOAD(it+2, Gfree);
        __builtin_amdgcn_sched_barrier(0);
        // MFMA (K=32) — FIN below may interleave (independent)
        {
            short8 bf0 = *(const short8*)&vals[cur][pxq*32 + n][8*g];
            short8 bf1 = *(const short8*)&vals[cur][pxq*32 + 16 + n][8*g];
#pragma unroll
            for (int rf = 0; rf < 4; ++rf) {
                short8 af = *(const short8*)&wslab[cur][(ch*64 + rf*16 + n)*36 + 8*g];
                acc[rf][0] = __builtin_amdgcn_mfma_f32_16x16x32_bf16(af, bf0, acc[rf][0], 0,0,0);
                acc[rf][1] = __builtin_amdgcn_mfma_f32_16x16x32_bf16(af, bf1, acc[rf][1], 0,0,0);
            }
        }
        if (it < 35) FIN(it+1, Gheld, nxt);
        if (it < 34) {
            asm volatile("s_waitcnt vmcnt(4) lgkmcnt(0)" ::: "memory");
            __builtin_amdgcn_s_barrier();
            __builtin_amdgcn_sched_barrier(0);
        } else if (it == 34) {
            asm volatile("s_waitcnt vmcnt(0) lgkmcnt(0)" ::: "memory");
            __builtin_amdgcn_s_barrier();
            __builtin_amdgcn_sched_barrier(0);
        }
    };
#pragma unroll 1
    for (int t = 0; t < 18; ++t) {
        BODY(2*t,     GA, GB);
        BODY(2*t + 1, GB, GA);
    }

    // epilogue
#pragma unroll
    for (int rf = 0; rf < 4; ++rf) {
#pragma unroll
        for (int pxb = 0; pxb < 2; ++pxb) {
            const int px = pxq*32 + pxb*16 + n;
#pragma unroll
            for (int r = 0; r < 4; ++r) {
                const int cout = ch*64 + rf*16 + 4*g + r;
                out[((b*NCOUT + cout)*NH + ho)*NW + px] = acc[rf][pxb][r] + bias[cout];
            }
        }
    }
}

// ---------------------------------------------------------------------------
extern "C" void kernel_launch(void* const* d_in, const int* in_sizes, int n_in,
                              void* d_out, int out_size, void* d_ws, size_t ws_size,
                              hipStream_t stream)
{
    const float* x      = (const float*)d_in[0];
    const float* w_off  = (const float*)d_in[1];
    const float* b_off  = (const float*)d_in[2];
    const float* weight = (const float*)d_in[3];
    const float* bias   = (const float*)d_in[4];
    float* out = (float*)d_out;
    float* ws  = (float*)d_ws;

    hipLaunchKernelGGL(wtrans_kernel, dim3(972), dim3(256), 0, stream,
                       w_off, weight, ws);
    hipLaunchKernelGGL(xtrans_kernel, dim3(1024), dim3(256), 0, stream,
                       x, ws);
    hipLaunchKernelGGL(fused_kernel, dim3(NB*NH), dim3(512), 0, stream,
                       b_off, bias, ws, out);
}

// Round 13
// 99.796 us; speedup vs baseline: 1.7732x; 1.7732x over previous
//
#include <hip/hip_runtime.h>
#include <math.h>

#define NB 4
#define NC 128
#define NH 128
#define NW 128
#define NHW (NH*NW)
#define NCOUT 128

// ws float offsets
#define SY_OFF 0
#define SX_OFF 1179648
#define MK_OFF 2359296
#define WOFF_OFF 3538944    // 36 slabs [64][36] bf16 (offset-conv W)
#define WMAIN_OFF 3580416   // 36 slabs [128][36] bf16 (main W)
#define XT_OFF 3663360      // bf16 xT[b][cg16][y][x][8ch] : 8388608 shorts

typedef short short8 __attribute__((ext_vector_type(8)));
typedef float f32x4 __attribute__((ext_vector_type(4)));

__device__ inline short f2bf(float f) {
    unsigned u = __float_as_uint(f);
    u = (u + 0x7FFFu + ((u >> 16) & 1u)) >> 16;   // RNE
    return (short)u;
}
__device__ inline unsigned pack2(float lo, float hi) {
    unsigned r;
    asm("v_cvt_pk_bf16_f32 %0, %1, %2" : "=v"(r) : "v"(lo), "v"(hi));
    return r;
}
__device__ inline float bflo(unsigned u) { return __uint_as_float(u << 16); }
__device__ inline float bfhi(unsigned u) { return __uint_as_float(u & 0xffff0000u); }
__device__ inline unsigned pkf16(float a, float b) {
    auto h = __builtin_amdgcn_cvt_pkrtz(a, b);
    unsigned r; __builtin_memcpy(&r, &h, 4); return r;
}
__device__ inline float f16f(unsigned s) {
    unsigned short us = (unsigned short)s;
    __fp16 h; __builtin_memcpy(&h, &us, 2); return (float)h;
}
__device__ inline void gload_lds16(const void* g, void* l) {
    __builtin_amdgcn_global_load_lds(
        (const __attribute__((address_space(1))) unsigned int*)g,
        (__attribute__((address_space(3))) unsigned int*)l, 16, 0, 0);
}

// ---------------------------------------------------------------------------
// wtrans: offset table 36 slabs [64][36] + main table 36 slabs [128][36] padded
// ---------------------------------------------------------------------------
__global__ void wtrans_kernel(const float* __restrict__ w_off,
                              const float* __restrict__ weight,
                              float* __restrict__ ws)
{
    int i = blockIdx.x * 256 + threadIdx.x;
    if (i < 36*2304) {
        int s = i / 2304, rem = i - s*2304;
        int row = rem / 36, c = rem - row*36;
        int chunk = s / 9, k2 = s - 9*chunk;
        float v = (row < 54 && c < 32) ? w_off[(row*NC + chunk*32 + c)*9 + k2] : 0.f;
        ((short*)(ws + WOFF_OFF))[i] = f2bf(v);
    } else if (i < 36*2304 + 36*4608) {
        int j = i - 36*2304;
        int s = j / 4608, rem = j - s*4608;
        int row = rem / 36, c = rem - row*36;
        int chunk = s / 9, k2 = s - 9*chunk;
        float v = (c < 32) ? weight[(row*NC + chunk*32 + c)*9 + k2] : 0.f;
        ((short*)(ws + WMAIN_OFF))[j] = f2bf(v);
    }
}

// ---------------------------------------------------------------------------
// xtrans: x NCHW fp32 -> xT[b][cg][y][x][8ch] bf16. Pure BW.
// ---------------------------------------------------------------------------
__global__ __launch_bounds__(256) void xtrans_kernel(
    const float* __restrict__ x, float* __restrict__ ws)
{
    short* xT = (short*)(ws + XT_OFF);
    const int bid = blockIdx.x;
    const int ys = bid & 15, cg = (bid >> 4) & 15, b = bid >> 8;
    const int col = threadIdx.x & 127, rr = threadIdx.x >> 7;
    const float* xb = x + ((long)(b*NC + cg*8))*NHW;
#pragma unroll
    for (int yy = 0; yy < 4; ++yy) {
        const int y = ys*8 + yy*2 + rr;
        const float* p = xb + y*NW + col;
        float v[8];
#pragma unroll
        for (int q = 0; q < 8; ++q) v[q] = p[q*NHW];
        uint4 u = make_uint4(pack2(v[0],v[1]), pack2(v[2],v[3]),
                             pack2(v[4],v[5]), pack2(v[6],v[7]));
        *(uint4*)&xT[(((long)(b*16+cg)*NH + y)*NW + col)*8] = u;
    }
}

// ---------------------------------------------------------------------------
// offconv: 3x3 conv (54 ch pad 64) as pure GEMM over xT. (R8 structure)
// ---------------------------------------------------------------------------
__global__ __launch_bounds__(512, 4) void offconv_kernel(
    float* __restrict__ ws, const float* __restrict__ b_off)
{
    __shared__ short wslab[2][2304];
    int bid = blockIdx.x;
    bid = (bid & 7) * 64 + (bid >> 3);      // XCD swizzle
    const int b   = bid >> 7;
    const int ho  = bid & 127;
    const int tid = threadIdx.x;
    const int lane = tid & 63;
    const int wid = tid >> 6;
    const int n = lane & 15, g = lane >> 4;
    const int px = wid*16 + n;
    const short* woff = (const short*)(ws + WOFF_OFF);
    const char*  xTb  = (const char*)((const short*)(ws + XT_OFF) + (long)b*16*NHW*8);

    f32x4 acc[4];
#pragma unroll
    for (int rf = 0; rf < 4; ++rf) acc[rf] = (f32x4){0.f,0.f,0.f,0.f};

    auto DMA = [&](int it, int buf) {
        if (tid < 288) gload_lds16(woff + it*2304 + tid*8, &wslab[buf][tid*8]);
    };
    auto LOADB = [&](int it) -> short8 {
        const int chunk = it/9, k2 = it - 9*chunk;
        const int y = ho + k2/3 - 1, xc = px + (k2%3) - 1;
        short8 bf = (short8){0,0,0,0,0,0,0,0};
        if ((unsigned)y < NH && (unsigned)xc < NW)
            bf = *(const short8*)(xTb + ((long)(chunk*4 + g)*NHW + y*NW + xc)*16);
        return bf;
    };

    DMA(0, 0);
    short8 bcur = LOADB(0);
    __syncthreads();

#pragma unroll 1
    for (int it = 0; it < 36; ++it) {
        const int cur = it & 1, nxt = cur ^ 1;
        short8 bnext;
        if (it < 35) { DMA(it+1, nxt); bnext = LOADB(it+1); }
        __builtin_amdgcn_sched_barrier(0);
#pragma unroll
        for (int rf = 0; rf < 4; ++rf) {
            short8 af = *(const short8*)&wslab[cur][(rf*16 + n)*36 + 8*g];
            acc[rf] = __builtin_amdgcn_mfma_f32_16x16x32_bf16(af, bcur, acc[rf], 0,0,0);
        }
        __syncthreads();
        bcur = bnext;
    }

#pragma unroll
    for (int rf = 0; rf < 4; ++rf) {
#pragma unroll
        for (int r = 0; r < 4; ++r) {
            int cout = 16*rf + 4*g + r;
            if (cout >= 54) continue;
            float v = acc[rf][r] + b_off[cout];
            if (cout < 36) {
                int og = cout / 18, rem = cout - 18*og;
                int k2c = rem >> 1, d = cout & 1;
                float base = d ? (float)(px - 1 + (k2c % 3))
                              : (float)(ho - 1 + (k2c / 3));
                ws[(d ? SX_OFF : SY_OFF) + (((b*2+og)*9 + k2c)*NHW) + ho*NW + px] = v + base;
            } else {
                int cc = cout - 36;
                int og = cc / 9, k2c = cc - 9*og;
                ws[MK_OFF + (((b*2+og)*9 + k2c)*NHW) + ho*NW + px] = 1.f/(1.f+expf(-v));
            }
        }
    }
}

// ---------------------------------------------------------------------------
// deform: block = (b, ho, half-row): 64 px x 128 cout, 256 threads = 4 waves.
// SWAPPED MFMA: sampled data = A-operand, kept in the SAMPLING thread's own
// registers (wave w = px 16w..16w+15; thread (n,g) = px 16w+n, ch 8g..8g+7).
// No vals LDS buffer, no ds_write. Weights = B-operand from DMA'd LDS slabs.
// LDS 36.9KB -> 4 blocks/CU, 4 independent barrier groups.
// ---------------------------------------------------------------------------
__global__ __launch_bounds__(256, 4) void deform_kernel(
    const float* __restrict__ ws_c, float* __restrict__ ws,
    const float* __restrict__ bias, float* __restrict__ out)
{
    __shared__ short4 pI[18][64];        // 9216 B (element offsets)
    __shared__ uint2  pWp[18][64];       // 9216 B (4 x f16 weights)
    __shared__ short  wslab[2][4608];    // 18432 B, [128][36] padded rows

    int bid = blockIdx.x;
    bid = (bid & 7) * 128 + (bid >> 3);     // XCD swizzle (1024 = 8*128)
    const int b   = bid >> 8;
    const int ho  = (bid >> 1) & 127;
    const int wb  = (bid & 1) * 64;
    const int tid = threadIdx.x;
    const int lane = tid & 63;
    const int wid = tid >> 6;               // 0..3
    const int n = lane & 15, g = lane >> 4;
    const int pxl = 16*wid + n;             // thread's local pixel 0..63
    const short* wmn = (const short*)(ws + WMAIN_OFF);
    const char*  xTb = (const char*)((const short*)(ws + XT_OFF) + (long)b*16*NHW*8);

    f32x4 acc[8];
#pragma unroll
    for (int rf = 0; rf < 8; ++rf) acc[rf] = (f32x4){0.f,0.f,0.f,0.f};

    // slab DMA: 9216 B = 256x2x16 + 64x16
    auto DMA = [&](int slabIdx, int buf) {
        const short* src = wmn + slabIdx*4608;
        gload_lds16(src + tid*8, &wslab[buf][tid*8]);
        gload_lds16(src + 2048 + tid*8, &wslab[buf][2048 + tid*8]);
        if (tid < 64) gload_lds16(src + 4096 + tid*8, &wslab[buf][4096 + tid*8]);
    };

    // issue 4 corner gathers for iter j (thread's own pixel, 8 ch)
#define GLOAD(j, G0, G1, G2, G3) do {                                   \
        const int row_ = ((j)/18)*9 + (j)%9;                            \
        const int chunk_ = (j)/9;                                       \
        const short4 I_ = pI[row_][pxl];                                \
        const char* xp_ = xTb + (long)(chunk_*4 + g)*(NHW*16);          \
        G0 = *(const uint4*)(xp_ + (((int)I_.x) << 4));                 \
        G1 = *(const uint4*)(xp_ + (((int)I_.y) << 4));                 \
        G2 = *(const uint4*)(xp_ + (((int)I_.z) << 4));                 \
        G3 = *(const uint4*)(xp_ + (((int)I_.w) << 4));                 \
    } while (0)

    // interpolate -> A-fragment (8 bf16) in registers
#define FIN(j, G0, G1, G2, G3, Adst) do {                               \
        const int row_ = ((j)/18)*9 + (j)%9;                            \
        const uint2 wp_ = *(const uint2*)&pWp[row_][pxl];               \
        const float W0_ = f16f(wp_.x), W1_ = f16f(wp_.x >> 16);         \
        const float W2_ = f16f(wp_.y), W3_ = f16f(wp_.y >> 16);         \
        uint4 u_; unsigned* up_ = (unsigned*)&u_;                       \
        const unsigned* a_ = (const unsigned*)&G0;                      \
        const unsigned* b_ = (const unsigned*)&G1;                      \
        const unsigned* c_ = (const unsigned*)&G2;                      \
        const unsigned* d_ = (const unsigned*)&G3;                      \
        _Pragma("unroll")                                               \
        for (int e = 0; e < 4; ++e) {                                   \
            float lo = W0_*bflo(a_[e]) + W1_*bflo(b_[e])                \
                     + W2_*bflo(c_[e]) + W3_*bflo(d_[e]);               \
            float hi = W0_*bfhi(a_[e]) + W1_*bfhi(b_[e])                \
                     + W2_*bfhi(c_[e]) + W3_*bfhi(d_[e]);               \
            up_[e] = pack2(lo, hi);                                     \
        }                                                               \
        __builtin_memcpy(&Adst, &u_, 16);                               \
    } while (0)

    DMA(0, 0);   // overlaps param build; drained by __syncthreads below

    // ---- build bilinear params for BOTH og halves (this block's 64 px)
    for (int e = tid; e < 1152; e += 256) {
        const int row = e >> 6, p = e & 63;
        const int og = row / 9, k2 = row - 9*og;
        const int sidx = (((b*2+og)*9 + k2)*NHW) + ho*NW + wb + p;
        const float sy = ws[SY_OFF + sidx];
        const float sx = ws[SX_OFF + sidx];
        const float m  = ws[MK_OFF + sidx];
        const float y0f = floorf(sy), x0f = floorf(sx);
        const float ly = sy - y0f, lx = sx - x0f;
        const int y0 = (int)y0f, x0i = (int)x0f;
        const int y1 = y0 + 1, x1 = x0i + 1;
        const bool vy0 = (unsigned)y0 < NH, vy1 = (unsigned)y1 < NH;
        const bool vx0 = (unsigned)x0i < NW, vx1 = (unsigned)x1 < NW;
        const int cy0 = min(max(y0,0),NH-1), cy1 = min(max(y1,0),NH-1);
        const int cx0 = min(max(x0i,0),NW-1), cx1 = min(max(x1,0),NW-1);
        pI[row][p] = make_short4(
            (short)(cy0*NW + cx0), (short)(cy0*NW + cx1),
            (short)(cy1*NW + cx0), (short)(cy1*NW + cx1));
        const float W0 = (vy0 && vx0) ? (1.f-ly)*(1.f-lx)*m : 0.f;
        const float W1 = (vy0 && vx1) ? (1.f-ly)*lx*m       : 0.f;
        const float W2 = (vy1 && vx0) ? ly*(1.f-lx)*m       : 0.f;
        const float W3 = (vy1 && vx1) ? ly*lx*m             : 0.f;
        pWp[row][p] = make_uint2(pkf16(W0, W1), pkf16(W2, W3));
    }
    __syncthreads();    // params ready; DMA(0) drained block-wide

    uint4 Ga0, Ga1, Ga2, Ga3, Gb0, Gb1, Gb2, Gb3;
    short8 Acur, Anxt;
    GLOAD(0, Ga0, Ga1, Ga2, Ga3);
    FIN(0, Ga0, Ga1, Ga2, Ga3, Acur);      // auto vmcnt(0): G(0) ready
    GLOAD(1, Gb0, Gb1, Gb2, Gb3);          // in flight across iters

    // steady-state: at entry to BODY(it): A(it) ready, G(it+1) in Gheld.
#define BODY(it, Ain, Aout, H0, H1, H2, H3, F0, F1, F2, F3) do {        \
        const int cur_ = (it) & 1, nxt_ = cur_ ^ 1;                     \
        if ((it) < 35) DMA((it)+1, nxt_);                               \
        if ((it) < 34) GLOAD((it)+2, F0, F1, F2, F3);                   \
        __builtin_amdgcn_sched_barrier(0);                              \
        _Pragma("unroll")                                               \
        for (int rf = 0; rf < 8; ++rf) {                                \
            short8 bf = *(const short8*)&wslab[cur_][(16*rf + n)*36 + 8*g]; \
            acc[rf] = __builtin_amdgcn_mfma_f32_16x16x32_bf16(Ain, bf, acc[rf], 0,0,0); \
        }                                                               \
        if ((it) < 35) FIN((it)+1, H0, H1, H2, H3, Aout);               \
        if ((it) < 34) {                                                \
            asm volatile("s_waitcnt vmcnt(4) lgkmcnt(0)" ::: "memory"); \
            __builtin_amdgcn_s_barrier();                               \
            __builtin_amdgcn_sched_barrier(0);                          \
        } else if ((it) == 34) {                                        \
            asm volatile("s_waitcnt vmcnt(0) lgkmcnt(0)" ::: "memory"); \
            __builtin_amdgcn_s_barrier();                               \
            __builtin_amdgcn_sched_barrier(0);                          \
        }                                                               \
    } while (0)

#pragma unroll 1
    for (int t = 0; t < 18; ++t) {
        BODY(2*t,     Acur, Anxt, Gb0, Gb1, Gb2, Gb3, Ga0, Ga1, Ga2, Ga3);
        BODY(2*t + 1, Anxt, Acur, Ga0, Ga1, Ga2, Ga3, Gb0, Gb1, Gb2, Gb3);
    }
#undef BODY
#undef GLOAD
#undef FIN

    // ---- epilogue: D row = px (4g+r), col = cout (16rf+n) -> float4 stores
#pragma unroll
    for (int rf = 0; rf < 8; ++rf) {
        const int cout = 16*rf + n;
        const float bb = bias[cout];
        float4 o = make_float4(acc[rf][0]+bb, acc[rf][1]+bb,
                               acc[rf][2]+bb, acc[rf][3]+bb);
        *(float4*)&out[((b*NCOUT + cout)*NH + ho)*NW + wb + 16*wid + 4*g] = o;
    }
}

// ---------------------------------------------------------------------------
extern "C" void kernel_launch(void* const* d_in, const int* in_sizes, int n_in,
                              void* d_out, int out_size, void* d_ws, size_t ws_size,
                              hipStream_t stream)
{
    const float* x      = (const float*)d_in[0];
    const float* w_off  = (const float*)d_in[1];
    const float* b_off  = (const float*)d_in[2];
    const float* weight = (const float*)d_in[3];
    const float* bias   = (const float*)d_in[4];
    float* out = (float*)d_out;
    float* ws  = (float*)d_ws;

    hipLaunchKernelGGL(wtrans_kernel, dim3(972), dim3(256), 0, stream,
                       w_off, weight, ws);
    hipLaunchKernelGGL(xtrans_kernel, dim3(1024), dim3(256), 0, stream,
                       x, ws);
    hipLaunchKernelGGL(offconv_kernel, dim3(NB*NH), dim3(512), 0, stream,
                       ws, b_off);
    hipLaunchKernelGGL(deform_kernel, dim3(NB*NH*2), dim3(256), 0, stream,
                       ws, ws, bias, out);
}

// Round 14
// 94.939 us; speedup vs baseline: 1.8640x; 1.0512x over previous
//
#include <hip/hip_runtime.h>
#include <math.h>

#define NB 4
#define NC 128
#define NH 128
#define NW 128
#define NHW (NH*NW)
#define NCOUT 128

// ws float offsets
#define SY_OFF 0
#define SX_OFF 1179648
#define MK_OFF 2359296
#define WOFF_OFF 3538944    // 36 slabs [64][36] bf16 (offset-conv W)
#define WMAIN_OFF 3580416   // 36 slabs [128][36] bf16 (main W)
#define XT_OFF 3663360      // bf16 xT[b][cg16][y][x][8ch] : 8388608 shorts

typedef short short8 __attribute__((ext_vector_type(8)));
typedef float f32x4 __attribute__((ext_vector_type(4)));
typedef float f32x2 __attribute__((ext_vector_type(2)));

__device__ inline short f2bf(float f) {
    unsigned u = __float_as_uint(f);
    u = (u + 0x7FFFu + ((u >> 16) & 1u)) >> 16;   // RNE
    return (short)u;
}
__device__ inline unsigned pack2(float lo, float hi) {
    unsigned r;
    asm("v_cvt_pk_bf16_f32 %0, %1, %2" : "=v"(r) : "v"(lo), "v"(hi));
    return r;
}
__device__ inline unsigned pkf16(float a, float b) {
    auto h = __builtin_amdgcn_cvt_pkrtz(a, b);
    unsigned r; __builtin_memcpy(&r, &h, 4); return r;
}
__device__ inline float f16f(unsigned s) {
    unsigned short us = (unsigned short)s;
    __fp16 h; __builtin_memcpy(&h, &us, 2); return (float)h;
}
// packed f32 math (VOP3P)
__device__ inline f32x2 pkmul(f32x2 a, f32x2 b) {
    f32x2 d; asm("v_pk_mul_f32 %0, %1, %2" : "=v"(d) : "v"(a), "v"(b)); return d;
}
__device__ inline f32x2 pkfma(f32x2 a, f32x2 b, f32x2 c) {
    f32x2 d; asm("v_pk_fma_f32 %0, %1, %2, %3" : "=v"(d) : "v"(a), "v"(b), "v"(c)); return d;
}
// corner uint (2 bf16) -> {lo_ch, hi_ch} f32 pair; hi is RAW (mantissa noise <= 1 bf16 ulp)
__device__ inline f32x2 cpair(unsigned u) {
    f32x2 c; c.x = __uint_as_float(u << 16); c.y = __uint_as_float(u); return c;
}
__device__ inline void gload_lds16(const void* g, void* l) {
    __builtin_amdgcn_global_load_lds(
        (const __attribute__((address_space(1))) unsigned int*)g,
        (__attribute__((address_space(3))) unsigned int*)l, 16, 0, 0);
}

// ---------------------------------------------------------------------------
// wtrans: offset table 36 slabs [64][36] + main table 36 slabs [128][36] padded
// ---------------------------------------------------------------------------
__global__ void wtrans_kernel(const float* __restrict__ w_off,
                              const float* __restrict__ weight,
                              float* __restrict__ ws)
{
    int i = blockIdx.x * 256 + threadIdx.x;
    if (i < 36*2304) {
        int s = i / 2304, rem = i - s*2304;
        int row = rem / 36, c = rem - row*36;
        int chunk = s / 9, k2 = s - 9*chunk;
        float v = (row < 54 && c < 32) ? w_off[(row*NC + chunk*32 + c)*9 + k2] : 0.f;
        ((short*)(ws + WOFF_OFF))[i] = f2bf(v);
    } else if (i < 36*2304 + 36*4608) {
        int j = i - 36*2304;
        int s = j / 4608, rem = j - s*4608;
        int row = rem / 36, c = rem - row*36;
        int chunk = s / 9, k2 = s - 9*chunk;
        float v = (c < 32) ? weight[(row*NC + chunk*32 + c)*9 + k2] : 0.f;
        ((short*)(ws + WMAIN_OFF))[j] = f2bf(v);
    }
}

// ---------------------------------------------------------------------------
// xtrans: x NCHW fp32 -> xT[b][cg][y][x][8ch] bf16. Pure BW.
// ---------------------------------------------------------------------------
__global__ __launch_bounds__(256) void xtrans_kernel(
    const float* __restrict__ x, float* __restrict__ ws)
{
    short* xT = (short*)(ws + XT_OFF);
    const int bid = blockIdx.x;
    const int ys = bid & 15, cg = (bid >> 4) & 15, b = bid >> 8;
    const int col = threadIdx.x & 127, rr = threadIdx.x >> 7;
    const float* xb = x + ((long)(b*NC + cg*8))*NHW;
#pragma unroll
    for (int yy = 0; yy < 4; ++yy) {
        const int y = ys*8 + yy*2 + rr;
        const float* p = xb + y*NW + col;
        float v[8];
#pragma unroll
        for (int q = 0; q < 8; ++q) v[q] = p[q*NHW];
        uint4 u = make_uint4(pack2(v[0],v[1]), pack2(v[2],v[3]),
                             pack2(v[4],v[5]), pack2(v[6],v[7]));
        *(uint4*)&xT[(((long)(b*16+cg)*NH + y)*NW + col)*8] = u;
    }
}

// ---------------------------------------------------------------------------
// offconv: 3x3 conv (54 ch pad 64) as pure GEMM over xT.
// Counted-vmcnt barriers: B-loads stay in flight across the barrier.
// ---------------------------------------------------------------------------
__global__ __launch_bounds__(512, 4) void offconv_kernel(
    float* __restrict__ ws, const float* __restrict__ b_off)
{
    __shared__ short wslab[2][2304];
    int bid = blockIdx.x;
    bid = (bid & 7) * 64 + (bid >> 3);      // XCD swizzle
    const int b   = bid >> 7;
    const int ho  = bid & 127;
    const int tid = threadIdx.x;
    const int lane = tid & 63;
    const int wid = tid >> 6;
    const int n = lane & 15, g = lane >> 4;
    const int px = wid*16 + n;
    const short* woff = (const short*)(ws + WOFF_OFF);
    const char*  xTb  = (const char*)((const short*)(ws + XT_OFF) + (long)b*16*NHW*8);

    f32x4 acc[4];
#pragma unroll
    for (int rf = 0; rf < 4; ++rf) acc[rf] = (f32x4){0.f,0.f,0.f,0.f};

    auto DMA = [&](int it, int buf) {
        if (tid < 288) gload_lds16(woff + it*2304 + tid*8, &wslab[buf][tid*8]);
    };
    auto LOADB = [&](int it) -> short8 {
        const int chunk = it/9, k2 = it - 9*chunk;
        const int y = ho + k2/3 - 1, xc = px + (k2%3) - 1;
        short8 bf = (short8){0,0,0,0,0,0,0,0};
        if ((unsigned)y < NH && (unsigned)xc < NW)
            bf = *(const short8*)(xTb + ((long)(chunk*4 + g)*NHW + y*NW + xc)*16);
        return bf;
    };

    DMA(0, 0);
    short8 bcur = LOADB(0);
    asm volatile("s_waitcnt vmcnt(1) lgkmcnt(0)" ::: "memory");   // DMA(0) done, B(0) flies
    __builtin_amdgcn_s_barrier();
    __builtin_amdgcn_sched_barrier(0);

#pragma unroll 1
    for (int it = 0; it < 36; ++it) {
        const int cur = it & 1, nxt = cur ^ 1;
        short8 bnext;
        if (it < 35) { DMA(it+1, nxt); bnext = LOADB(it+1); }
        __builtin_amdgcn_sched_barrier(0);
#pragma unroll
        for (int rf = 0; rf < 4; ++rf) {
            short8 af = *(const short8*)&wslab[cur][(rf*16 + n)*36 + 8*g];
            acc[rf] = __builtin_amdgcn_mfma_f32_16x16x32_bf16(af, bcur, acc[rf], 0,0,0);
        }
        __builtin_amdgcn_sched_barrier(0);
        if (it < 35) {
            asm volatile("s_waitcnt vmcnt(1) lgkmcnt(0)" ::: "memory");  // drain DMA only
            __builtin_amdgcn_s_barrier();
            __builtin_amdgcn_sched_barrier(0);
        }
        bcur = bnext;
    }

#pragma unroll
    for (int rf = 0; rf < 4; ++rf) {
#pragma unroll
        for (int r = 0; r < 4; ++r) {
            int cout = 16*rf + 4*g + r;
            if (cout >= 54) continue;
            float v = acc[rf][r] + b_off[cout];
            if (cout < 36) {
                int og = cout / 18, rem = cout - 18*og;
                int k2c = rem >> 1, d = cout & 1;
                float base = d ? (float)(px - 1 + (k2c % 3))
                              : (float)(ho - 1 + (k2c / 3));
                ws[(d ? SX_OFF : SY_OFF) + (((b*2+og)*9 + k2c)*NHW) + ho*NW + px] = v + base;
            } else {
                int cc = cout - 36;
                int og = cc / 9, k2c = cc - 9*og;
                ws[MK_OFF + (((b*2+og)*9 + k2c)*NHW) + ho*NW + px] = 1.f/(1.f+expf(-v));
            }
        }
    }
}

// ---------------------------------------------------------------------------
// deform: block = (b, ho): 128 px x 128 cout, 512 threads = 8 waves.
// Swapped MFMA: thread (wid,n,g) samples px=16*wid+n, ch 8g..8g+7 -> its own
// A-fragment in registers (no vals LDS). Weights = B from DMA'd LDS slabs.
// pk_fma FIN, raw-hi bf16 unpack, 2-deep gather prefetch, counted vmcnt.
// ---------------------------------------------------------------------------
__global__ __launch_bounds__(512, 4) void deform_kernel(
    float* __restrict__ ws, const float* __restrict__ bias,
    float* __restrict__ out)
{
    __shared__ short4 pI[18][128];        // 18432 B (element offsets)
    __shared__ uint2  pWp[18][128];       // 18432 B (4 x f16 weights)
    __shared__ short  wslab[2][4608];     // 18432 B, [128][36] padded rows

    int bid = blockIdx.x;
    bid = (bid & 7) * 64 + (bid >> 3);      // XCD swizzle (512 = 8*64)
    const int b   = bid >> 7;
    const int ho  = bid & 127;
    const int tid = threadIdx.x;
    const int lane = tid & 63;
    const int wid = tid >> 6;               // 0..7
    const int n = lane & 15, g = lane >> 4;
    const int pxl = 16*wid + n;             // thread's pixel 0..127
    const short* wmn = (const short*)(ws + WMAIN_OFF);
    const char*  xTb = (const char*)((const short*)(ws + XT_OFF) + (long)b*16*NHW*8);

    f32x4 acc[8];
#pragma unroll
    for (int rf = 0; rf < 8; ++rf) acc[rf] = (f32x4){0.f,0.f,0.f,0.f};

    auto DMA = [&](int slabIdx, int buf) {
        const short* src = wmn + slabIdx*4608;
        gload_lds16(src + tid*8, &wslab[buf][tid*8]);
        if (tid < 64) gload_lds16(src + 4096 + tid*8, &wslab[buf][4096 + tid*8]);
    };

#define GLOAD(j, G0, G1, G2, G3) do {                                   \
        const int row_ = ((j)/18)*9 + (j)%9;                            \
        const int chunk_ = (j)/9;                                       \
        const short4 I_ = pI[row_][pxl];                                \
        const char* xp_ = xTb + (long)(chunk_*4 + g)*(NHW*16);          \
        G0 = *(const uint4*)(xp_ + (((int)I_.x) << 4));                 \
        G1 = *(const uint4*)(xp_ + (((int)I_.y) << 4));                 \
        G2 = *(const uint4*)(xp_ + (((int)I_.z) << 4));                 \
        G3 = *(const uint4*)(xp_ + (((int)I_.w) << 4));                 \
    } while (0)

#define FIN(j, G0, G1, G2, G3, Adst) do {                               \
        const int row_ = ((j)/18)*9 + (j)%9;                            \
        const uint2 wp_ = *(const uint2*)&pWp[row_][pxl];               \
        const float w0s = f16f(wp_.x), w1s = f16f(wp_.x >> 16);         \
        const float w2s = f16f(wp_.y), w3s = f16f(wp_.y >> 16);         \
        const f32x2 W0_ = {w0s, w0s}, W1_ = {w1s, w1s};                 \
        const f32x2 W2_ = {w2s, w2s}, W3_ = {w3s, w3s};                 \
        uint4 u_; unsigned* up_ = (unsigned*)&u_;                       \
        const unsigned* a_ = (const unsigned*)&G0;                      \
        const unsigned* b_ = (const unsigned*)&G1;                      \
        const unsigned* c_ = (const unsigned*)&G2;                      \
        const unsigned* d_ = (const unsigned*)&G3;                      \
        _Pragma("unroll")                                               \
        for (int e = 0; e < 4; ++e) {                                   \
            f32x2 r_ = pkmul(cpair(d_[e]), W3_);                        \
            r_ = pkfma(cpair(c_[e]), W2_, r_);                          \
            r_ = pkfma(cpair(b_[e]), W1_, r_);                          \
            r_ = pkfma(cpair(a_[e]), W0_, r_);                          \
            up_[e] = pack2(r_.x, r_.y);                                 \
        }                                                               \
        __builtin_memcpy(&Adst, &u_, 16);                               \
    } while (0)

    DMA(0, 0);   // overlaps param build

    // ---- build bilinear params for BOTH og halves (128 px)
    for (int e = tid; e < 2304; e += 512) {
        const int row = e >> 7, p = e & 127;
        const int og = row / 9, k2 = row - 9*og;
        const int sidx = (((b*2+og)*9 + k2)*NHW) + ho*NW + p;
        const float sy = ws[SY_OFF + sidx];
        const float sx = ws[SX_OFF + sidx];
        const float m  = ws[MK_OFF + sidx];
        const float y0f = floorf(sy), x0f = floorf(sx);
        const float ly = sy - y0f, lx = sx - x0f;
        const int y0 = (int)y0f, x0i = (int)x0f;
        const int y1 = y0 + 1, x1 = x0i + 1;
        const bool vy0 = (unsigned)y0 < NH, vy1 = (unsigned)y1 < NH;
        const bool vx0 = (unsigned)x0i < NW, vx1 = (unsigned)x1 < NW;
        const int cy0 = min(max(y0,0),NH-1), cy1 = min(max(y1,0),NH-1);
        const int cx0 = min(max(x0i,0),NW-1), cx1 = min(max(x1,0),NW-1);
        pI[row][p] = make_short4(
            (short)(cy0*NW + cx0), (short)(cy0*NW + cx1),
            (short)(cy1*NW + cx0), (short)(cy1*NW + cx1));
        const float W0 = (vy0 && vx0) ? (1.f-ly)*(1.f-lx)*m : 0.f;
        const float W1 = (vy0 && vx1) ? (1.f-ly)*lx*m       : 0.f;
        const float W2 = (vy1 && vx0) ? ly*(1.f-lx)*m       : 0.f;
        const float W3 = (vy1 && vx1) ? ly*lx*m             : 0.f;
        pWp[row][p] = make_uint2(pkf16(W0, W1), pkf16(W2, W3));
    }
    __syncthreads();    // params ready; DMA(0) drained

    uint4 Ga0, Ga1, Ga2, Ga3, Gb0, Gb1, Gb2, Gb3;
    short8 Acur, Anxt;
    GLOAD(0, Ga0, Ga1, Ga2, Ga3);
    FIN(0, Ga0, Ga1, Ga2, Ga3, Acur);      // waits G(0)
    GLOAD(1, Gb0, Gb1, Gb2, Gb3);          // in flight across iters

    // steady state: entry to BODY(it): A(it) ready, G(it+1) in Gheld.
#define BODY(it, Ain, Aout, H0, H1, H2, H3, F0, F1, F2, F3) do {        \
        const int cur_ = (it) & 1, nxt_ = cur_ ^ 1;                     \
        if ((it) < 35) DMA((it)+1, nxt_);                               \
        if ((it) < 34) GLOAD((it)+2, F0, F1, F2, F3);                   \
        __builtin_amdgcn_sched_barrier(0);                              \
        _Pragma("unroll")                                               \
        for (int rf = 0; rf < 8; ++rf) {                                \
            short8 bf = *(const short8*)&wslab[cur_][(16*rf + n)*36 + 8*g]; \
            acc[rf] = __builtin_amdgcn_mfma_f32_16x16x32_bf16(Ain, bf, acc[rf], 0,0,0); \
        }                                                               \
        if ((it) < 35) FIN((it)+1, H0, H1, H2, H3, Aout);               \
        if ((it) < 34) {                                                \
            asm volatile("s_waitcnt vmcnt(4) lgkmcnt(0)" ::: "memory"); \
            __builtin_amdgcn_s_barrier();                               \
            __builtin_amdgcn_sched_barrier(0);                          \
        } else if ((it) == 34) {                                        \
            asm volatile("s_waitcnt vmcnt(0) lgkmcnt(0)" ::: "memory"); \
            __builtin_amdgcn_s_barrier();                               \
            __builtin_amdgcn_sched_barrier(0);                          \
        }                                                               \
    } while (0)

#pragma unroll 1
    for (int t = 0; t < 18; ++t) {
        BODY(2*t,     Acur, Anxt, Gb0, Gb1, Gb2, Gb3, Ga0, Ga1, Ga2, Ga3);
        BODY(2*t + 1, Anxt, Acur, Ga0, Ga1, Ga2, Ga3, Gb0, Gb1, Gb2, Gb3);
    }
#undef BODY
#undef GLOAD
#undef FIN

    // ---- epilogue: D row = px (4g+r), col = cout (16rf+n) -> float4 stores
#pragma unroll
    for (int rf = 0; rf < 8; ++rf) {
        const int cout = 16*rf + n;
        const float bb = bias[cout];
        float4 o = make_float4(acc[rf][0]+bb, acc[rf][1]+bb,
                               acc[rf][2]+bb, acc[rf][3]+bb);
        *(float4*)&out[((b*NCOUT + cout)*NH + ho)*NW + 16*wid + 4*g] = o;
    }
}

// ---------------------------------------------------------------------------
extern "C" void kernel_launch(void* const* d_in, const int* in_sizes, int n_in,
                              void* d_out, int out_size, void* d_ws, size_t ws_size,
                              hipStream_t stream)
{
    const float* x      = (const float*)d_in[0];
    const float* w_off  = (const float*)d_in[1];
    const float* b_off  = (const float*)d_in[2];
    const float* weight = (const float*)d_in[3];
    const float* bias   = (const float*)d_in[4];
    float* out = (float*)d_out;
    float* ws  = (float*)d_ws;

    hipLaunchKernelGGL(wtrans_kernel, dim3(972), dim3(256), 0, stream,
                       w_off, weight, ws);
    hipLaunchKernelGGL(xtrans_kernel, dim3(1024), dim3(256), 0, stream,
                       x, ws);
    hipLaunchKernelGGL(offconv_kernel, dim3(NB*NH), dim3(512), 0, stream,
                       ws, b_off);
    hipLaunchKernelGGL(deform_kernel, dim3(NB*NH), dim3(512), 0, stream,
                       ws, bias, out);
}

// Round 15
// 93.302 us; speedup vs baseline: 1.8967x; 1.0175x over previous
//
#include <hip/hip_runtime.h>
#include <math.h>

#define NB 4
#define NC 128
#define NH 128
#define NW 128
#define NHW (NH*NW)
#define NCOUT 128

// ws float offsets
#define SY_OFF 0
#define SX_OFF 1179648
#define MK_OFF 2359296
#define WOFF_OFF 3538944    // 36 slabs [64][36] bf16 (offset-conv W)
#define WMAIN_OFF 3580416   // 36 slabs [128][36] bf16 (main W)
#define XT_OFF 3663360      // bf16 xT[b][cg16][y][x][8ch] : 8388608 shorts

typedef short short8 __attribute__((ext_vector_type(8)));
typedef float f32x4 __attribute__((ext_vector_type(4)));
typedef float f32x2 __attribute__((ext_vector_type(2)));

__device__ inline short f2bf(float f) {
    unsigned u = __float_as_uint(f);
    u = (u + 0x7FFFu + ((u >> 16) & 1u)) >> 16;   // RNE
    return (short)u;
}
__device__ inline unsigned pack2(float lo, float hi) {
    unsigned r;
    asm("v_cvt_pk_bf16_f32 %0, %1, %2" : "=v"(r) : "v"(lo), "v"(hi));
    return r;
}
__device__ inline unsigned pkf16(float a, float b) {
    auto h = __builtin_amdgcn_cvt_pkrtz(a, b);
    unsigned r; __builtin_memcpy(&r, &h, 4); return r;
}
__device__ inline float f16f(unsigned s) {
    unsigned short us = (unsigned short)s;
    __fp16 h; __builtin_memcpy(&h, &us, 2); return (float)h;
}
__device__ inline f32x2 pkmul(f32x2 a, f32x2 b) {
    f32x2 d; asm("v_pk_mul_f32 %0, %1, %2" : "=v"(d) : "v"(a), "v"(b)); return d;
}
__device__ inline f32x2 pkfma(f32x2 a, f32x2 b, f32x2 c) {
    f32x2 d; asm("v_pk_fma_f32 %0, %1, %2, %3" : "=v"(d) : "v"(a), "v"(b), "v"(c)); return d;
}
// corner uint (2 bf16) -> {lo_ch, hi_ch}; hi is RAW (mantissa noise <= 1 bf16 ulp)
__device__ inline f32x2 cpair(unsigned u) {
    f32x2 c; c.x = __uint_as_float(u << 16); c.y = __uint_as_float(u); return c;
}
__device__ inline void gload_lds16(const void* g, void* l) {
    __builtin_amdgcn_global_load_lds(
        (const __attribute__((address_space(1))) unsigned int*)g,
        (__attribute__((address_space(3))) unsigned int*)l, 16, 0, 0);
}

// ---------------------------------------------------------------------------
// wtrans: offset table 36 slabs [64][36] + main table 36 slabs [128][36] padded
// ---------------------------------------------------------------------------
__global__ void wtrans_kernel(const float* __restrict__ w_off,
                              const float* __restrict__ weight,
                              float* __restrict__ ws)
{
    int i = blockIdx.x * 256 + threadIdx.x;
    if (i < 36*2304) {
        int s = i / 2304, rem = i - s*2304;
        int row = rem / 36, c = rem - row*36;
        int chunk = s / 9, k2 = s - 9*chunk;
        float v = (row < 54 && c < 32) ? w_off[(row*NC + chunk*32 + c)*9 + k2] : 0.f;
        ((short*)(ws + WOFF_OFF))[i] = f2bf(v);
    } else if (i < 36*2304 + 36*4608) {
        int j = i - 36*2304;
        int s = j / 4608, rem = j - s*4608;
        int row = rem / 36, c = rem - row*36;
        int chunk = s / 9, k2 = s - 9*chunk;
        float v = (c < 32) ? weight[(row*NC + chunk*32 + c)*9 + k2] : 0.f;
        ((short*)(ws + WMAIN_OFF))[j] = f2bf(v);
    }
}

// ---------------------------------------------------------------------------
// xtrans: x NCHW fp32 -> xT[b][cg][y][x][8ch] bf16. Pure BW.
// ---------------------------------------------------------------------------
__global__ __launch_bounds__(256) void xtrans_kernel(
    const float* __restrict__ x, float* __restrict__ ws)
{
    short* xT = (short*)(ws + XT_OFF);
    const int bid = blockIdx.x;
    const int ys = bid & 15, cg = (bid >> 4) & 15, b = bid >> 8;
    const int col = threadIdx.x & 127, rr = threadIdx.x >> 7;
    const float* xb = x + ((long)(b*NC + cg*8))*NHW;
#pragma unroll
    for (int yy = 0; yy < 4; ++yy) {
        const int y = ys*8 + yy*2 + rr;
        const float* p = xb + y*NW + col;
        float v[8];
#pragma unroll
        for (int q = 0; q < 8; ++q) v[q] = p[q*NHW];
        uint4 u = make_uint4(pack2(v[0],v[1]), pack2(v[2],v[3]),
                             pack2(v[4],v[5]), pack2(v[6],v[7]));
        *(uint4*)&xT[(((long)(b*16+cg)*NH + y)*NW + col)*8] = u;
    }
}

// ---------------------------------------------------------------------------
// offconv: 3x3 conv (54 ch pad 64) as pure GEMM over xT. (R8-exact structure)
// ---------------------------------------------------------------------------
__global__ __launch_bounds__(512, 4) void offconv_kernel(
    float* __restrict__ ws, const float* __restrict__ b_off)
{
    __shared__ short wslab[2][2304];
    int bid = blockIdx.x;
    bid = (bid & 7) * 64 + (bid >> 3);      // XCD swizzle
    const int b   = bid >> 7;
    const int ho  = bid & 127;
    const int tid = threadIdx.x;
    const int lane = tid & 63;
    const int wid = tid >> 6;
    const int n = lane & 15, g = lane >> 4;
    const int px = wid*16 + n;
    const short* woff = (const short*)(ws + WOFF_OFF);
    const char*  xTb  = (const char*)((const short*)(ws + XT_OFF) + (long)b*16*NHW*8);

    f32x4 acc[4];
#pragma unroll
    for (int rf = 0; rf < 4; ++rf) acc[rf] = (f32x4){0.f,0.f,0.f,0.f};

    auto DMA = [&](int it, int buf) {
        if (tid < 288) gload_lds16(woff + it*2304 + tid*8, &wslab[buf][tid*8]);
    };
    auto LOADB = [&](int it) -> short8 {
        const int chunk = it/9, k2 = it - 9*chunk;
        const int y = ho + k2/3 - 1, xc = px + (k2%3) - 1;
        short8 bf = (short8){0,0,0,0,0,0,0,0};
        if ((unsigned)y < NH && (unsigned)xc < NW)
            bf = *(const short8*)(xTb + ((long)(chunk*4 + g)*NHW + y*NW + xc)*16);
        return bf;
    };

    DMA(0, 0);
    short8 bcur = LOADB(0);
    __syncthreads();

#pragma unroll 1
    for (int it = 0; it < 36; ++it) {
        const int cur = it & 1, nxt = cur ^ 1;
        short8 bnext;
        if (it < 35) { DMA(it+1, nxt); bnext = LOADB(it+1); }
        __builtin_amdgcn_sched_barrier(0);
#pragma unroll
        for (int rf = 0; rf < 4; ++rf) {
            short8 af = *(const short8*)&wslab[cur][(rf*16 + n)*36 + 8*g];
            acc[rf] = __builtin_amdgcn_mfma_f32_16x16x32_bf16(af, bcur, acc[rf], 0,0,0);
        }
        __syncthreads();
        bcur = bnext;
    }

#pragma unroll
    for (int rf = 0; rf < 4; ++rf) {
#pragma unroll
        for (int r = 0; r < 4; ++r) {
            int cout = 16*rf + 4*g + r;
            if (cout >= 54) continue;
            float v = acc[rf][r] + b_off[cout];
            if (cout < 36) {
                int og = cout / 18, rem = cout - 18*og;
                int k2c = rem >> 1, d = cout & 1;
                float base = d ? (float)(px - 1 + (k2c % 3))
                              : (float)(ho - 1 + (k2c / 3));
                ws[(d ? SX_OFF : SY_OFF) + (((b*2+og)*9 + k2c)*NHW) + ho*NW + px] = v + base;
            } else {
                int cc = cout - 36;
                int og = cc / 9, k2c = cc - 9*og;
                ws[MK_OFF + (((b*2+og)*9 + k2c)*NHW) + ho*NW + px] = 1.f/(1.f+expf(-v));
            }
        }
    }
}

// ---------------------------------------------------------------------------
// deform: block = (b, ho): 128 px x 128 cout, 512 threads = 8 waves.
// Swapped MFMA (A = sampled data in registers). All 9 k2-slabs of a cin-chunk
// resident in LDS -> 9 BARRIER-FREE iterations per phase; waves free-run and
// de-phase (FIN VALU || gather TA || MFMA overlap across waves).
// Only 4 DMA phases + 2 param rebuilds synchronize. 1 block/CU (101KB LDS).
// ---------------------------------------------------------------------------
__global__ __launch_bounds__(512, 2) void deform_kernel(
    float* __restrict__ ws, const float* __restrict__ bias,
    float* __restrict__ out)
{
    __shared__ short4 pI[9][128];         //  9216 B (element offsets, per og)
    __shared__ uint2  pWp[9][128];        //  9216 B (4 x f16 weights, per og)
    __shared__ short  slabs[9][4608];     // 82944 B: 9 k2-slabs [128][36]

    int bid = blockIdx.x;
    bid = (bid & 7) * 64 + (bid >> 3);      // XCD swizzle (512 = 8*64)
    const int b   = bid >> 7;
    const int ho  = bid & 127;
    const int tid = threadIdx.x;
    const int lane = tid & 63;
    const int wid = tid >> 6;               // 0..7
    const int n = lane & 15, g = lane >> 4;
    const int pxl = 16*wid + n;             // thread's pixel 0..127
    const short* wmn = (const short*)(ws + WMAIN_OFF);
    const char*  xTb = (const char*)((const short*)(ws + XT_OFF) + (long)b*16*NHW*8);

    f32x4 acc[8];
#pragma unroll
    for (int rf = 0; rf < 8; ++rf) acc[rf] = (f32x4){0.f,0.f,0.f,0.f};

    // DMA all 9 slabs for a chunk: 5184 x 16B units
    auto DMAC = [&](int chunk) {
        const short* src = wmn + chunk*9*4608;
        short* dst = &slabs[0][0];
#pragma unroll 1
        for (int u = tid; u < 5184; u += 512)
            gload_lds16(src + u*8, dst + u*8);
    };

#define GLOAD(chunk, k2, G0, G1, G2, G3) do {                           \
        const short4 I_ = pI[(k2)][pxl];                                \
        const char* xp_ = xTb + (long)((chunk)*4 + g)*(NHW*16);         \
        G0 = *(const uint4*)(xp_ + (((int)I_.x) << 4));                 \
        G1 = *(const uint4*)(xp_ + (((int)I_.y) << 4));                 \
        G2 = *(const uint4*)(xp_ + (((int)I_.z) << 4));                 \
        G3 = *(const uint4*)(xp_ + (((int)I_.w) << 4));                 \
    } while (0)

#define FIN(k2, G0, G1, G2, G3, Adst) do {                              \
        const uint2 wp_ = *(const uint2*)&pWp[(k2)][pxl];               \
        const float w0s = f16f(wp_.x), w1s = f16f(wp_.x >> 16);         \
        const float w2s = f16f(wp_.y), w3s = f16f(wp_.y >> 16);         \
        const f32x2 W0_ = {w0s, w0s}, W1_ = {w1s, w1s};                 \
        const f32x2 W2_ = {w2s, w2s}, W3_ = {w3s, w3s};                 \
        uint4 u_; unsigned* up_ = (unsigned*)&u_;                       \
        const unsigned* a_ = (const unsigned*)&G0;                      \
        const unsigned* b_ = (const unsigned*)&G1;                      \
        const unsigned* c_ = (const unsigned*)&G2;                      \
        const unsigned* d_ = (const unsigned*)&G3;                      \
        _Pragma("unroll")                                               \
        for (int e = 0; e < 4; ++e) {                                   \
            f32x2 r_ = pkmul(cpair(d_[e]), W3_);                        \
            r_ = pkfma(cpair(c_[e]), W2_, r_);                          \
            r_ = pkfma(cpair(b_[e]), W1_, r_);                          \
            r_ = pkfma(cpair(a_[e]), W0_, r_);                          \
            up_[e] = pack2(r_.x, r_.y);                                 \
        }                                                               \
        __builtin_memcpy(&Adst, &u_, 16);                               \
    } while (0)

#define MFMA8(Ain, k2) do {                                             \
        _Pragma("unroll")                                               \
        for (int rf = 0; rf < 8; ++rf) {                                \
            short8 bf = *(const short8*)&slabs[(k2)][(16*rf + n)*36 + 8*g]; \
            acc[rf] = __builtin_amdgcn_mfma_f32_16x16x32_bf16(Ain, bf, acc[rf], 0,0,0); \
        }                                                               \
    } while (0)

// one barrier-free iteration inside a phase
#define PBODY(k2, chunk, Ain, Aout, H0,H1,H2,H3, F0,F1,F2,F3) do {      \
        if ((k2) < 7) GLOAD(chunk, (k2)+2, F0, F1, F2, F3);             \
        MFMA8(Ain, k2);                                                 \
        if ((k2) < 8) FIN((k2)+1, H0, H1, H2, H3, Aout);                \
    } while (0)

    uint4 Ga0, Ga1, Ga2, Ga3, Gb0, Gb1, Gb2, Gb3;
    short8 Acur, Anxt;

#pragma unroll 1
    for (int og = 0; og < 2; ++og) {
        if (og) __syncthreads();        // prior phase reads of slabs+params done
        DMAC(og*2);                     // overlaps param build
        // ---- build bilinear params for this og (9 rows x 128 px)
        for (int e = tid; e < 1152; e += 512) {
            const int row = e >> 7, p = e & 127;
            const int sidx = (((b*2+og)*9 + row)*NHW) + ho*NW + p;
            const float sy = ws[SY_OFF + sidx];
            const float sx = ws[SX_OFF + sidx];
            const float m  = ws[MK_OFF + sidx];
            const float y0f = floorf(sy), x0f = floorf(sx);
            const float ly = sy - y0f, lx = sx - x0f;
            const int y0 = (int)y0f, x0i = (int)x0f;
            const int y1 = y0 + 1, x1 = x0i + 1;
            const bool vy0 = (unsigned)y0 < NH, vy1 = (unsigned)y1 < NH;
            const bool vx0 = (unsigned)x0i < NW, vx1 = (unsigned)x1 < NW;
            const int cy0 = min(max(y0,0),NH-1), cy1 = min(max(y1,0),NH-1);
            const int cx0 = min(max(x0i,0),NW-1), cx1 = min(max(x1,0),NW-1);
            pI[row][p] = make_short4(
                (short)(cy0*NW + cx0), (short)(cy0*NW + cx1),
                (short)(cy1*NW + cx0), (short)(cy1*NW + cx1));
            const float W0 = (vy0 && vx0) ? (1.f-ly)*(1.f-lx)*m : 0.f;
            const float W1 = (vy0 && vx1) ? (1.f-ly)*lx*m       : 0.f;
            const float W2 = (vy1 && vx0) ? ly*(1.f-lx)*m       : 0.f;
            const float W3 = (vy1 && vx1) ? ly*lx*m             : 0.f;
            pWp[row][p] = make_uint2(pkf16(W0, W1), pkf16(W2, W3));
        }
        __syncthreads();                // params visible + DMA drained

#pragma unroll 1
        for (int cc = 0; cc < 2; ++cc) {
            const int chunk = og*2 + cc;
            if (cc) {
                __syncthreads();        // all waves done reading slabs
                DMAC(chunk);
                asm volatile("s_waitcnt vmcnt(0) lgkmcnt(0)" ::: "memory");
                __builtin_amdgcn_s_barrier();
                __builtin_amdgcn_sched_barrier(0);
            }
            // ---- phase: 9 barrier-free iterations
            GLOAD(chunk, 0, Ga0, Ga1, Ga2, Ga3);
            FIN(0, Ga0, Ga1, Ga2, Ga3, Acur);
            GLOAD(chunk, 1, Gb0, Gb1, Gb2, Gb3);
            PBODY(0, chunk, Acur, Anxt, Gb0,Gb1,Gb2,Gb3, Ga0,Ga1,Ga2,Ga3);
            PBODY(1, chunk, Anxt, Acur, Ga0,Ga1,Ga2,Ga3, Gb0,Gb1,Gb2,Gb3);
            PBODY(2, chunk, Acur, Anxt, Gb0,Gb1,Gb2,Gb3, Ga0,Ga1,Ga2,Ga3);
            PBODY(3, chunk, Anxt, Acur, Ga0,Ga1,Ga2,Ga3, Gb0,Gb1,Gb2,Gb3);
            PBODY(4, chunk, Acur, Anxt, Gb0,Gb1,Gb2,Gb3, Ga0,Ga1,Ga2,Ga3);
            PBODY(5, chunk, Anxt, Acur, Ga0,Ga1,Ga2,Ga3, Gb0,Gb1,Gb2,Gb3);
            PBODY(6, chunk, Acur, Anxt, Gb0,Gb1,Gb2,Gb3, Ga0,Ga1,Ga2,Ga3);
            PBODY(7, chunk, Anxt, Acur, Ga0,Ga1,Ga2,Ga3, Gb0,Gb1,Gb2,Gb3);
            PBODY(8, chunk, Acur, Anxt, Gb0,Gb1,Gb2,Gb3, Ga0,Ga1,Ga2,Ga3);
        }
    }
#undef PBODY
#undef MFMA8
#undef GLOAD
#undef FIN

    // ---- epilogue: D row = px (4g+r), col = cout (16rf+n) -> float4 stores
#pragma unroll
    for (int rf = 0; rf < 8; ++rf) {
        const int cout = 16*rf + n;
        const float bb = bias[cout];
        float4 o = make_float4(acc[rf][0]+bb, acc[rf][1]+bb,
                               acc[rf][2]+bb, acc[rf][3]+bb);
        *(float4*)&out[((b*NCOUT + cout)*NH + ho)*NW + 16*wid + 4*g] = o;
    }
}

// ---------------------------------------------------------------------------
extern "C" void kernel_launch(void* const* d_in, const int* in_sizes, int n_in,
                              void* d_out, int out_size, void* d_ws, size_t ws_size,
                              hipStream_t stream)
{
    const float* x      = (const float*)d_in[0];
    const float* w_off  = (const float*)d_in[1];
    const float* b_off  = (const float*)d_in[2];
    const float* weight = (const float*)d_in[3];
    const float* bias   = (const float*)d_in[4];
    float* out = (float*)d_out;
    float* ws  = (float*)d_ws;

    hipLaunchKernelGGL(wtrans_kernel, dim3(972), dim3(256), 0, stream,
                       w_off, weight, ws);
    hipLaunchKernelGGL(xtrans_kernel, dim3(1024), dim3(256), 0, stream,
                       x, ws);
    hipLaunchKernelGGL(offconv_kernel, dim3(NB*NH), dim3(512), 0, stream,
                       ws, b_off);
    hipLaunchKernelGGL(deform_kernel, dim3(NB*NH), dim3(512), 0, stream,
                       ws, bias, out);
}